// Round 8
// baseline (687.046 us; speedup 1.0000x reference)
//
#include <hip/hip_runtime.h>

#define NSTEP 730
#define NGRID 1000
#define NPAR  13
#define PRECS 1e-5f

// parameters (NSTEP, NGRID, 13, MU=8): idx(t,g,i,m) = t*104000 + g*104 + i*8 + m
#define PAR_TSTRIDE 104000u
#define PAR_GSTRIDE 104u
// x (NSTEP, NGRID, 3): idx(t,g,c) = t*3000 + g*3 + c
#define X_TSTRIDE 3000u

#define G5    5                  // steps per group (fast path)
#define NGRP5 146                // 730/5 groups

#define GSTEPS 10                // legacy generic path group size
#define NGROUP 73

constexpr float LB_[NPAR] = {1.0f, 50.0f, 0.05f, 0.01f, 0.001f, 0.2f, 0.0f,
                             0.0f, -2.5f, 0.5f, 0.0f, 0.0f, 0.3f};
constexpr float UB_[NPAR] = {6.0f, 1000.0f, 0.9f, 0.5f, 0.2f, 1.0f, 10.0f,
                             100.0f, 2.5f, 10.0f, 0.1f, 0.2f, 5.0f};

__device__ __forceinline__ float fast_rcp(float x)  { return __builtin_amdgcn_rcpf(x); }
__device__ __forceinline__ float fast_exp2(float x) { return __builtin_amdgcn_exp2f(x); }
__device__ __forceinline__ float fast_log2(float x) { return __builtin_amdgcn_logf(x); }

__device__ __forceinline__ int mod13(int v) {
    int r = v % NPAR;
    if (r < 0) r += NPAR;
    return r;
}

// ---- 8-lane (mu) sum stages.
template <int CTRL>
__device__ __forceinline__ float dpp_xadd(float v) {
    int r = __builtin_amdgcn_update_dpp(0, __float_as_int(v), CTRL, 0xF, 0xF, true);
    return v + __int_as_float(r);
}
// Legacy (verified) version with ds_swizzle xor4 — used by generic paths.
__device__ __forceinline__ float mu8_sum(float v) {
    v = dpp_xadd<0xB1>(v);   // lane ^= 1
    v = dpp_xadd<0x4E>(v);   // lane ^= 2
    int s = __builtin_amdgcn_ds_swizzle(__float_as_int(v), 0x101F); // lane ^= 4
    return v + __int_as_float(s);
}
// Pure-DPP version (harness-verified R2/R6): after xor1/xor2 all 4 lanes of a
// quad hold bitwise-equal partial sums; row_half_mirror pairs with the other
// quad of the 8-group -> bitwise-identical total. No LDS pipe usage.
__device__ __forceinline__ float mu8_sum_dpp(float v) {
    v = dpp_xadd<0xB1>(v);    // lane ^= 1
    v = dpp_xadd<0x4E>(v);    // lane ^= 2
    v = dpp_xadd<0x141>(v);   // row_half_mirror: cross-quad within 8-group
    return v;
}

// One HBV step (legacy helper for generic paths).
__device__ __forceinline__ float hbv_step_core(
    float P_, float T_, float ET_,
    float BETA, float FC, float K0, float K1, float K2,
    float PERCc, float UZL, float TT, float CFMAX, float CFR, float CWH,
    float BETAET, float rcpFC, float rcpLPFC,
    float& SP, float& MW, float& SM, float& SUZ, float& SLZ)
{
    float dT    = T_ - TT;
    float RAIN  = (T_ >= TT) ? P_ : 0.f;
    float SNOW  = P_ - RAIN;
    SP += SNOW;
    float cm    = CFMAX * dT;
    float melt  = fminf(fmaxf(cm, 0.f), SP);
    MW += melt; SP -= melt;
    float refr  = fminf(fmaxf(-CFR * cm, 0.f), MW);
    SP += refr; MW -= refr;
    float tosoil = fmaxf(MW - CWH * SP, 0.f);
    MW -= tosoil;
    float soilw  = fminf(fast_exp2(BETA * fast_log2(SM * rcpFC)), 1.f);
    float rt     = RAIN + tosoil;
    float rech   = rt * soilw;
    SM += rt - rech;
    float excess = fmaxf(SM - FC, 0.f);
    SM -= excess;
    float evapf  = fminf(fast_exp2(BETAET * fast_log2(SM * rcpLPFC)), 1.f);
    float ETact  = fminf(SM, ET_ * evapf);
    SM = fmaxf(SM - ETact, PRECS);
    SUZ += rech + excess;
    float PERC = fminf(SUZ, PERCc);
    SUZ -= PERC;
    float Q0 = K0 * fmaxf(SUZ - UZL, 0.f);
    SUZ -= Q0;
    float Q1 = K1 * SUZ;
    SUZ -= Q1;
    SLZ += PERC;
    float Q2 = K2 * SLZ;
    SLZ -= Q2;
    return Q0 + Q1 + Q2;
}

// ---- Specialized {12,0} step: EXACT formula text of the verified consumer.
// Shared by both interleaved chains so the arithmetic stays in one place.
__device__ __forceinline__ float hbv_step_fast(
    float Pj, float Tj, float ET, float rv0 /*param12 raw*/, float rv1 /*param0 raw*/,
    float TT, float CFMAX, float CC, float CWH, float FC,
    float K0, float K1, float K2, float PERCc, float UZL,
    float l2rcpFC, float l2rcpLPF,
    float& SP, float& MW, float& SM, float& SUZ, float& SLZ)
{
    constexpr float lbB = LB_[0],  dvB = UB_[0]  - LB_[0];
    constexpr float lbE = LB_[12], dvE = UB_[12] - LB_[12];
    float dT     = Tj - TT;
    float RAIN   = (dT >= 0.f) ? Pj : 0.f;
    float SNOW   = Pj - RAIN;
    float MAXCM  = fmaxf(CFMAX * dT, 0.f);
    float MAXRF  = fmaxf(-CC * dT, 0.f);
    float BETAET = fmaf(rv0, dvE, lbE);
    float BETA   = fmaf(rv1, dvB, lbB);
    float bbc    = BETA * l2rcpFC;
    float ebc    = BETAET * l2rcpLPF;
    SP += SNOW;
    float melt = fminf(MAXCM, SP);
    MW += melt; SP -= melt;
    float refr = fminf(MAXRF, MW);
    SP += refr; MW -= refr;
    float tosoil = fmaxf(fmaf(-CWH, SP, MW), 0.f);
    MW -= tosoil;
    float rt    = RAIN + tosoil;
    float soilw = fast_exp2(fmaf(BETA, fast_log2(SM), bbc));
    float rech  = rt * soilw;
    float SM_mid = SM + rt - rech;
    float SM_ae  = fminf(SM_mid, FC);
    float excess = SM_mid - SM_ae;
    float evapf  = fminf(fast_exp2(fmaf(BETAET, fast_log2(SM_ae), ebc)), 1.f);
    SM = fmaxf(fmaf(-ET, evapf, SM_ae), PRECS);
    SUZ += rech + excess;
    float PERC = fminf(SUZ, PERCc);
    float SUZp = SUZ - PERC;
    float Q0   = K0 * fmaxf(SUZp - UZL, 0.f);
    float SUZq = SUZp - Q0;
    float Q1   = K1 * SUZq;
    SUZ = SUZq - Q1;
    SLZ += PERC;
    float Q2 = K2 * SLZ;
    SLZ -= Q2;
    return (Q0 + Q1) + Q2;
}

// ---- Generic NTD=2 single-wave body (verified fallback for idx != {12,0}).
__device__ void hbv_generic2(
    const float* __restrict__ x, const float* __restrict__ par,
    int staind, int idx0, int idx1, float* __restrict__ out, int g, int m)
{
    const unsigned cpar = (unsigned)g * PAR_GSTRIDE + (unsigned)m;
    const unsigned g3   = (unsigned)g * 3u;

    float lb0 = 0.f, dv0 = 0.f, lb1 = 0.f, dv1 = 0.f;
    float sel0[NPAR], sel1[NPAR];
#pragma unroll
    for (int i = 0; i < NPAR; ++i) {
        sel0[i] = (idx0 == i) ? 1.f : 0.f;
        sel1[i] = (idx1 == i && idx1 != idx0) ? 1.f : 0.f;
        if (idx0 == i) { lb0 = LB_[i]; dv0 = UB_[i] - LB_[i]; }
        if (idx1 == i) { lb1 = LB_[i]; dv1 = UB_[i] - LB_[i]; }
    }
    const unsigned off0 = (unsigned)idx0 * 8u, off1 = (unsigned)idx1 * 8u;

    float basep[NPAR];
    const unsigned sbase = (unsigned)staind * PAR_TSTRIDE + cpar;
#pragma unroll
    for (int i = 0; i < NPAR; ++i) {
        float fxv = fmaf(par[sbase + (unsigned)i * 8u], UB_[i] - LB_[i], LB_[i]);
        basep[i] = fxv * (1.f - sel0[i] - sel1[i]);
    }

    float bP[2][GSTEPS], bT[2][GSTEPS], bEv[2][GSTEPS];
    float bS0[2][GSTEPS], bS1[2][GSTEPS];
    float SP = 0.001f, MW = 0.001f, SM = 0.001f, SUZ = 0.001f, SLZ = 0.001f;

    auto load = [&](int b, int t0) {
#pragma unroll
        for (int j = 0; j < GSTEPS; ++j) {
            unsigned t  = (unsigned)(t0 + j);
            unsigned xo = t * X_TSTRIDE + g3;
            bP[b][j]  = x[xo];
            bT[b][j]  = x[xo + 1u];
            bEv[b][j] = x[xo + 2u];
            unsigned po = t * PAR_TSTRIDE + cpar;
            bS0[b][j] = par[po + off0];
            bS1[b][j] = par[po + off1];
        }
    };
    auto compute = [&](int b, int t0) {
        float ql[GSTEPS];
#pragma unroll
        for (int j = 0; j < GSTEPS; ++j) {
            float sv0 = fmaf(bS0[b][j], dv0, lb0);
            float sv1 = fmaf(bS1[b][j], dv1, lb1);
            float pr[NPAR];
#pragma unroll
            for (int i = 0; i < NPAR; ++i)
                pr[i] = fmaf(sel1[i], sv1, fmaf(sel0[i], sv0, basep[i]));
            float rcpFC   = fast_rcp(pr[1]);
            float rcpLPFC = fast_rcp(pr[5] * pr[1]);
            ql[j] = hbv_step_core(bP[b][j], bT[b][j], bEv[b][j],
                                  pr[0], pr[1], pr[2], pr[3], pr[4], pr[6],
                                  pr[7], pr[8], pr[9], pr[10], pr[11], pr[12],
                                  rcpFC, rcpLPFC, SP, MW, SM, SUZ, SLZ);
        }
#pragma unroll
        for (int j = 0; j < GSTEPS; ++j) {
            float s = mu8_sum(ql[j]);
            if (m == 0)
                out[(unsigned)(t0 + j) * (unsigned)NGRID + (unsigned)g] = s * 0.125f;
        }
    };

    load(0, 0);
    for (int gp = 0; gp < NGROUP; gp += 2) {
        if (gp + 1 < NGROUP) load(1, (gp + 1) * GSTEPS);
        compute(0, gp * GSTEPS);
        if (gp + 2 < NGROUP) load(0, (gp + 2) * GSTEPS);
        if (gp + 1 < NGROUP) compute(1, (gp + 1) * GSTEPS);
    }
}

// ==== 2-chains-per-lane single-wave kernel (latency-bubble filling).
// 63 blocks x 64 lanes. chainA = tid (0..4031), chainB = tid + 4032
// (4032..7999; tid >= 3968 has no valid B -> loads clamped to chain 7999,
// stores guarded). 4032 % 8 == 0 so both chains' 8-lane mu-groups align with
// the DPP reduction. The two chains' step bodies are independent -> the
// scheduler interleaves them, filling the ~350-cycle serial-chain bubbles.
// 2 VGPR buffers x G5 steps x 2 chains, prefetch distance 1 group:
// ~40 VMEM outstanding (< vmcnt limit 63), coverage ~1600 cyc > ~900 HBM.
__global__ __launch_bounds__(64, 1) void hbv_fast3(
    const float* __restrict__ x, const float* __restrict__ par,
    const int* __restrict__ staind_p, const int* __restrict__ tdlst_p,
    float* __restrict__ out)
{
    const int tid = blockIdx.x * 64 + threadIdx.x;    // 63*64 = 4032 lanes
    const int m   = threadIdx.x & 7;                  // mu index (A and B alike)
    const int gA  = tid >> 3;                         // 0..503
    const bool validB = (tid < 3968);
    const int chainB  = validB ? tid + 4032 : 7999;   // clamp -> valid memory
    const int gB  = chainB >> 3;
    const int mB  = chainB & 7;                       // == m when validB

    const int staind = __builtin_amdgcn_readfirstlane(staind_p[0]);
    const int idx0   = __builtin_amdgcn_readfirstlane(mod13(tdlst_p[0] - 1));
    const int idx1   = __builtin_amdgcn_readfirstlane(mod13(tdlst_p[1] - 1));

    if (!(idx0 == 12 && idx1 == 0)) {                 // grid-uniform branch
        hbv_generic2(x, par, staind, idx0, idx1, out, gA, m);
        if (validB) hbv_generic2(x, par, staind, idx0, idx1, out, gB, mB);
        return;
    }

    const unsigned cparA = (unsigned)gA * PAR_GSTRIDE + (unsigned)m;
    const unsigned g3A   = (unsigned)gA * 3u;
    const unsigned cparB = (unsigned)gB * PAR_GSTRIDE + (unsigned)mB;
    const unsigned g3B   = (unsigned)gB * 3u;

    // staind-row params, scaled, per chain.
    float fxA[NPAR], fxB[NPAR];
    {
        const unsigned sbA = (unsigned)staind * PAR_TSTRIDE + cparA;
        const unsigned sbB = (unsigned)staind * PAR_TSTRIDE + cparB;
#pragma unroll
        for (int i = 0; i < NPAR; ++i) {
            fxA[i] = fmaf(par[sbA + (unsigned)i * 8u], UB_[i] - LB_[i], LB_[i]);
            fxB[i] = fmaf(par[sbB + (unsigned)i * 8u], UB_[i] - LB_[i], LB_[i]);
        }
    }
    // Derived constants (identical derivation to verified kernels).
    const float FCa = fxA[1], K0a = fxA[2], K1a = fxA[3], K2a = fxA[4],
                PCa = fxA[6], UZa = fxA[7], TTa = fxA[8], CFa = fxA[9],
                CWa = fxA[11];
    const float CCa = fxA[10] * fxA[9];
    const float lFa = fast_log2(fast_rcp(fxA[1]));
    const float lLa = fast_log2(fast_rcp(fxA[5] * fxA[1]));

    const float FCb = fxB[1], K0b = fxB[2], K1b = fxB[3], K2b = fxB[4],
                PCb = fxB[6], UZb = fxB[7], TTb = fxB[8], CFb = fxB[9],
                CWb = fxB[11];
    const float CCb = fxB[10] * fxB[9];
    const float lFb = fast_log2(fast_rcp(fxB[1]));
    const float lLb = fast_log2(fast_rcp(fxB[5] * fxB[1]));

    // Staging: 2 buffers x 5 steps x 5 values x 2 chains = 100 VGPR.
    float aP[2][G5], aT[2][G5], aE[2][G5], a0[2][G5], a1[2][G5];
    float bP[2][G5], bT[2][G5], bE[2][G5], b0[2][G5], b1[2][G5];

    float SPa = 0.001f, MWa = 0.001f, SMa = 0.001f, SUa = 0.001f, SLa = 0.001f;
    float SPb = 0.001f, MWb = 0.001f, SMb = 0.001f, SUb = 0.001f, SLb = 0.001f;

// BUF must be a LITERAL (0/1) so all indexing is compile-time (no scratch).
#define GLOAD2(BUF, grp)                                                   \
    {                                                                      \
        const int t0_ = (grp) * G5;                                        \
        const float* xa_ = x   + (unsigned)t0_ * X_TSTRIDE   + g3A;        \
        const float* pa_ = par + (unsigned)t0_ * PAR_TSTRIDE + cparA;      \
        const float* xb_ = x   + (unsigned)t0_ * X_TSTRIDE   + g3B;        \
        const float* pb_ = par + (unsigned)t0_ * PAR_TSTRIDE + cparB;      \
        _Pragma("unroll")                                                  \
        for (int j = 0; j < G5; ++j) {                                     \
            float3 va_ = *reinterpret_cast<const float3*>(xa_);            \
            aP[BUF][j] = va_.x; aT[BUF][j] = va_.y; aE[BUF][j] = va_.z;    \
            a1[BUF][j] = pa_[0];    /* param 0  raw (BETA)   */            \
            a0[BUF][j] = pa_[96];   /* param 12 raw (BETAET) */            \
            float3 vb_ = *reinterpret_cast<const float3*>(xb_);            \
            bP[BUF][j] = vb_.x; bT[BUF][j] = vb_.y; bE[BUF][j] = vb_.z;    \
            b1[BUF][j] = pb_[0];                                           \
            b0[BUF][j] = pb_[96];                                          \
            xa_ += X_TSTRIDE; pa_ += PAR_TSTRIDE;                          \
            xb_ += X_TSTRIDE; pb_ += PAR_TSTRIDE;                          \
        }                                                                  \
    }

#define COMP2(BUF, grp)                                                    \
    {                                                                      \
        const int t0_ = (grp) * G5;                                        \
        _Pragma("unroll")                                                  \
        for (int j = 0; j < G5; ++j) {                                     \
            float qa_ = hbv_step_fast(aP[BUF][j], aT[BUF][j], aE[BUF][j],  \
                                      a0[BUF][j], a1[BUF][j],              \
                                      TTa, CFa, CCa, CWa, FCa,             \
                                      K0a, K1a, K2a, PCa, UZa, lFa, lLa,   \
                                      SPa, MWa, SMa, SUa, SLa);            \
            float qb_ = hbv_step_fast(bP[BUF][j], bT[BUF][j], bE[BUF][j],  \
                                      b0[BUF][j], b1[BUF][j],              \
                                      TTb, CFb, CCb, CWb, FCb,             \
                                      K0b, K1b, K2b, PCb, UZb, lFb, lLb,   \
                                      SPb, MWb, SMb, SUb, SLb);            \
            float sa_ = mu8_sum_dpp(qa_);                                  \
            float sb_ = mu8_sum_dpp(qb_);                                  \
            const unsigned to_ = (unsigned)(t0_ + j) * (unsigned)NGRID;    \
            if (m == 0)                                                    \
                out[to_ + (unsigned)gA] = sa_ * 0.125f;                    \
            if (m == 0 && validB)                                          \
                out[to_ + (unsigned)gB] = sb_ * 0.125f;                    \
        }                                                                  \
    }

    // Pipeline: group k lives in buffer k&1 (literal via 2x-unrolled loop);
    // prefetch distance 1 group (~5 x ~330 cyc coverage > ~900 cyc HBM).
    GLOAD2(0, 0);
    int k = 0;
    for (int t = 0; t < 73; ++t) {       // 73 x 2 groups = 146
        if (k + 1 < NGRP5) GLOAD2(1, k + 1);
        COMP2(0, k); ++k;
        if (k + 1 < NGRP5) GLOAD2(0, k + 1);
        COMP2(1, k); ++k;
    }
#undef GLOAD2
#undef COMP2
}

// ---- Fallback kernel for n_td != 2 (unchanged, verified).
__global__ __launch_bounds__(64, 1) void hbv_scan_generic(
    const float* __restrict__ x, const float* __restrict__ par,
    const int* __restrict__ staind_p, const int* __restrict__ tdlst_p,
    int n_td, float* __restrict__ out)
{
    const int tid = blockIdx.x * 64 + threadIdx.x;
    const int g   = tid >> 3;
    const int m   = tid & 7;
    if (g >= NGRID) return;

    const int staind    = staind_p[0];
    const unsigned cpar = (unsigned)g * PAR_GSTRIDE + (unsigned)m;
    const unsigned g3   = (unsigned)g * 3u;

    unsigned off[NPAR], st[NPAR];
#pragma unroll
    for (int i = 0; i < NPAR; ++i) {
        bool vr = false;
        for (int j = 0; j < n_td; ++j)
            if (mod13(tdlst_p[j] - 1) == i) vr = true;
        off[i] = (vr ? 0u : (unsigned)staind * PAR_TSTRIDE) + cpar + (unsigned)i * 8u;
        st[i]  = vr ? PAR_TSTRIDE : 0u;
    }

    float SP = 0.001f, MW = 0.001f, SM = 0.001f, SUZ = 0.001f, SLZ = 0.001f;
    for (int t = 0; t < NSTEP; ++t) {
        unsigned xo = (unsigned)t * X_TSTRIDE + g3;
        float P_ = x[xo], T_ = x[xo + 1u], E_ = x[xo + 2u];
        float pr[NPAR];
#pragma unroll
        for (int i = 0; i < NPAR; ++i) {
            pr[i] = fmaf(par[off[i]], UB_[i] - LB_[i], LB_[i]);
            off[i] += st[i];
        }
        float rcpFC   = fast_rcp(pr[1]);
        float rcpLPFC = fast_rcp(pr[5] * pr[1]);
        float q = hbv_step_core(P_, T_, E_, pr[0], pr[1], pr[2], pr[3], pr[4],
                                pr[6], pr[7], pr[8], pr[9], pr[10], pr[11],
                                pr[12], rcpFC, rcpLPFC, SP, MW, SM, SUZ, SLZ);
        float s = mu8_sum(q);
        if (m == 0) out[(unsigned)t * (unsigned)NGRID + (unsigned)g] = s * 0.125f;
    }
}

extern "C" void kernel_launch(void* const* d_in, const int* in_sizes, int n_in,
                              void* d_out, int out_size, void* d_ws, size_t ws_size,
                              hipStream_t stream) {
    const float* x      = (const float*)d_in[0];
    const float* par    = (const float*)d_in[1];
    const int*   staind = (const int*)d_in[2];
    const int*   tdlst  = (const int*)d_in[3];
    float*       out    = (float*)d_out;
    const int n_td = in_sizes[3];

    if (n_td == 2) {
        hbv_fast3<<<63, 64, 0, stream>>>(x, par, staind, tdlst, out);
    } else {
        hbv_scan_generic<<<125, 64, 0, stream>>>(x, par, staind, tdlst,
                                                 n_td, out);
    }
}